// Round 10
// baseline (174.227 us; speedup 1.0000x reference)
//
#include <hip/hip_runtime.h>

// Problem: unbiased EWMA mean/var normalization over T, s:(16,2000,257,2) fp32.
// Layout: idx = ((n*T + t)*F + f)*C + c -> one n's data is CONTIGUOUS across
// (t, f, c); row per t = 514 floats = 2056 B.
//
// Strategy (v10 — contiguous streaming blocks; v9 machinery kept):
//  - v1-v9 post-mortem: five structurally different kernels (JIT loads, reg
//    prefetch, 2xTLP, nt / non-nt stores, LDS-DMA depth-2 with sound counted
//    waits) ALL converge to 2.5-2.65 TB/s. Ceiling is insensitive to
//    latency-depth, occupancy and store policy => it's the ACCESS PATTERN:
//    ~900 independent walkers issuing 256B bursts at 2056B stride -> HBM
//    row-buffer thrash -> ~41% of the 6.3 TB/s linear-stream ceiling.
//  - v10: block = (n, chunk), 576 threads (9 waves). The block's reads are a
//    single CONTIGUOUS span: staging = linear memcpy of 16-t rows (32896+pad
//    bytes/group) via global_load_lds 16B/lane, 36 uniform 1KB-tile ops/group
//    (4 per wave; op space padded to 36 so ALL waves have identical op counts
//    -> one vmcnt literal, no divergent wait paths). Compute is decoupled:
//    thread k owns series fc=k (active fc<514; waves' lanes read consecutive
//    LDS banks -> conflict-free; junk lanes 514-575 compute garbage, never
//    stored). Stores: 64 consecutive lanes -> contiguous 256B, block covers
//    the full 2056B row per t.
//  - Ring of NSLOT=3 LDS slots, stage-2-ahead (always issued, sources clamped
//    to array end-16 -> uniform counts, junk never consumed). Sound waits
//    (vmcnt retires in issue order; queue peak 40 << 63):
//      warm:   vmcnt(4)  = keep {stg(g+2)}, force stg(g+1). Exact.
//      output: vmcnt(20) = keep {stg(g+2)4, stores(g)16}, force stg(g+1) and
//              stores(g-1). Exact at pipeline fill AND steady state.
//      boundary (straddles t_out; chunk 1 only): vmcnt(0) full drain.
//  - y ping-pong (yA/yB) + post-wait keepalives: stores(g) stay in flight
//    through group g+1; their data regs must not be recycled until the g+1
//    wait retires them (compiler sees them dead after the asm store).
//  - No asm-written VGPR lives across a backedge (v7/v8 crash class): ds_read
//    outputs are consumed within the body after lgkmcnt(0)+sched_barrier.
//  - NCHUNK=7, WARM=512 (beta^512 ~ 5.9e-3): minimum-traffic geometry
//    (~181 MB HBM). Grid 16x7 = 112 blocks; 9 waves each.

#define NN 16
#define TT 2000
#define FCC 514
#define BPT 2056                  // bytes per t-row (514*4)
#define BETAF 0.99f
#define OMBF 0.01f
#define EPSF 1e-5f
#define NCHUNK 7
#define CLEN 286
#define WARM 512
#define G 16                      // t-steps per group
#define GRPB (G * BPT)            // 32896 real bytes per group
#define SLOTB 36864               // 36 * 1024 staged bytes (uniform op pad)
#define NSLOT 3

// beta^i, i=0..16 (folds to literals)
__device__ __constant__ const float BP[G + 1] = {
    1.0f, 0.99f, 0.9801f, 0.970299f, 0.96059601f, 0.9509900499f,
    0.941480149401f, 0.93206534790699f, 0.9227446944279201f,
    0.9134272474836409f, 0.9042929750088045f, 0.8952500452587165f,
    0.8862975448061293f, 0.877434569357868f, 0.8686602236642894f,
    0.8599736214276465f, 0.8513738852133700f
};

// read 16 x's for this thread's series from slot (g%3); asm = opaque to the
// compiler's waitcnt model; lgkmcnt(0)+sched_barrier pins consumers below.
#define READX                                                                \
    float x[G];                                                              \
    {                                                                        \
        unsigned a = ldsbase + (unsigned)((g % NSLOT) * SLOTB) + d           \
                   + (unsigned)fc * 4u;                                      \
        _Pragma("unroll")                                                    \
        for (int i = 0; i < G; ++i) {                                        \
            asm volatile("ds_read_b32 %0, %1" : "=v"(x[i]) : "v"(a));        \
            a += BPT;                                                        \
        }                                                                    \
        asm volatile("s_waitcnt lgkmcnt(0)" ::: "memory");                   \
        __builtin_amdgcn_sched_barrier(0);                                   \
    }

// per-group lane-invariant scalars (16 pipelined v_rcp, off the chain)
#define RCPB                                                                 \
    float rr[G];                                                             \
    _Pragma("unroll")                                                        \
    for (int i = 0; i < G; ++i)                                              \
        rr[i] = __builtin_amdgcn_rcpf(1.0f - btg * BP[i]);                   \
    btg *= BP[G];

#define KEEP16(Y)                                                            \
    asm volatile("" :: "v"(Y[0]), "v"(Y[1]), "v"(Y[2]), "v"(Y[3]),           \
                       "v"(Y[4]), "v"(Y[5]), "v"(Y[6]), "v"(Y[7]),           \
                       "v"(Y[8]), "v"(Y[9]), "v"(Y[10]), "v"(Y[11]),         \
                       "v"(Y[12]), "v"(Y[13]), "v"(Y[14]), "v"(Y[15]));

// one output-phase group: compute into Y, store, counted wait, barrier
#define BODY_OUT(Y)                                                          \
    {                                                                        \
        READX                                                                \
        STAGE(g + 2);                                                        \
        RCPB                                                                 \
        float* pg = Ofp + (size_t)t * FCC + fc;                              \
        _Pragma("unroll")                                                    \
        for (int i = 0; i < G; ++i) {                                        \
            const float xx = x[i];                                           \
            const float r  = rr[i];                                          \
            v1 = fmaf(BETAF, v1, OMBF * xx);                                 \
            const float v2 = v1 * r;                                         \
            const float dd = xx - v2;                                        \
            const float dp = xx - v2p;                                       \
            S = fmaf(OMBF * r, dd * dp - S, S);                              \
            S = fmaxf(S, 0.0f);                                              \
            Y[i] = dd * __builtin_amdgcn_rsqf(S + EPSF);                     \
            v2p = v2;                                                        \
            if (fc < FCC)                                                    \
                asm volatile("global_store_dword %0, %1, off"                \
                             :: "v"(pg + i * FCC), "v"(Y[i]));               \
        }                                                                    \
        /* keep {stg(g+2)4, stores(g)16}; force stg(g+1) + stores(g-1) */    \
        asm volatile("s_waitcnt vmcnt(20)" ::: "memory");                    \
        __builtin_amdgcn_sched_barrier(0);                                   \
        KEEP16(yA) KEEP16(yB)                                                \
        __builtin_amdgcn_s_barrier();                                        \
    }

__global__ __launch_bounds__(576, 1)
void ewma_kernel(const float* __restrict__ s, float* __restrict__ out) {
    __shared__ char lds[NSLOT * SLOTB];   // 110592 B -> 1 block/CU

    const int lane = threadIdx.x & 63;
    const int wid  = threadIdx.x >> 6;
    const int fc   = threadIdx.x;         // series within n; active if < 514
    const int n    = blockIdx.x;
    const int chunk = blockIdx.y;

    const int t_out = chunk * CLEN;
    int t_end = t_out + CLEN; if (t_end > TT) t_end = TT;
    int t0 = t_out - WARM;     if (t0 < 0) t0 = 0;

    const char* Bn     = (const char*)s + (size_t)n * TT * BPT;
    const char* send16 = (const char*)s + (size_t)NN * TT * BPT - 16;
    const unsigned d   = (unsigned)((t0 & 1) * 8);   // (t0*2056) & 15

    const unsigned ldsbase =
        (unsigned)(uintptr_t)(__attribute__((address_space(3))) char*)lds;

    // 16B-aligned global base of group 0's span (GRPB is a multiple of 16)
    const char* Astage0 = Bn + (size_t)t0 * BPT - d;

    // stage group k -> slot k%3: 36 uniform 1KB-tile ops (4 per wave), 16B/lane,
    // sources clamped to array end (junk tiles staged, never consumed).
    auto STAGE = [&](int k) {
        const char* A = Astage0 + (size_t)k * GRPB;
        char* slot = lds + (k % NSLOT) * SLOTB;
        #pragma unroll
        for (int j = 0; j < 4; ++j) {
            const int o = wid * 4 + j;               // 0..35, all waves equal
            const char* src = A + o * 1024 + lane * 16;
            if (src > send16) src = send16;
            __builtin_amdgcn_global_load_lds(
                (const __attribute__((address_space(1))) void*)src,
                (__attribute__((address_space(3))) void*)(slot + o * 1024),
                16, 0, 0);
        }
    };

    // btg = beta^(t0+1) via double binary exponentiation (once per thread)
    float btg;
    {
        double bd = 0.99, acc = 0.99;
        int e = t0;
        while (e) { if (e & 1) acc *= bd; bd *= bd; e >>= 1; }
        btg = (float)acc;
    }

    float v1 = 0.0f, v2p = 0.0f, S = 0.0f;
    float* Ofp = out + (size_t)n * TT * FCC;

    // ---- prologue: stage groups 0,1; force stg(0), keep stg(1) ----
    STAGE(0); STAGE(1);
    asm volatile("s_waitcnt vmcnt(4)" ::: "memory");
    __builtin_amdgcn_sched_barrier(0);
    __builtin_amdgcn_s_barrier();

    int t = t0, g = 0;

    // ---- warm phase (no stores; y dead-codes away) ----
    while (t + G <= t_out) {
        READX
        STAGE(g + 2);
        RCPB
        #pragma unroll
        for (int i = 0; i < G; ++i) {
            const float xx = x[i];
            const float r  = rr[i];
            v1 = fmaf(BETAF, v1, OMBF * xx);
            const float v2 = v1 * r;
            const float dd = xx - v2;
            const float dp = xx - v2p;
            S = fmaf(OMBF * r, dd * dp - S, S);
            S = fmaxf(S, 0.0f);
            v2p = v2;
        }
        asm volatile("s_waitcnt vmcnt(4)" ::: "memory");  // keep stg(g+2)
        __builtin_amdgcn_sched_barrier(0);
        __builtin_amdgcn_s_barrier();
        ++g; t += G;
    }

    // ---- boundary group (straddles t_out; chunk 1 only); full drain ----
    if (t < t_out && t + G <= t_end) {
        READX
        STAGE(g + 2);
        RCPB
        float* pg = Ofp + (size_t)t * FCC + fc;
        #pragma unroll
        for (int i = 0; i < G; ++i) {
            const float xx = x[i];
            const float r  = rr[i];
            v1 = fmaf(BETAF, v1, OMBF * xx);
            const float v2 = v1 * r;
            const float dd = xx - v2;
            const float dp = xx - v2p;
            S = fmaf(OMBF * r, dd * dp - S, S);
            S = fmaxf(S, 0.0f);
            const float y = dd * __builtin_amdgcn_rsqf(S + EPSF);
            v2p = v2;
            if (t + i >= t_out && fc < FCC)
                asm volatile("global_store_dword %0, %1, off"
                             :: "v"(pg + i * FCC), "v"(y));
        }
        asm volatile("s_waitcnt vmcnt(0)" ::: "memory");
        __builtin_amdgcn_sched_barrier(0);
        __builtin_amdgcn_s_barrier();
        ++g; t += G;
    }

    // ---- output phase: y ping-pong, uniform vmcnt(20) ----
    float yA[G], yB[G];
    #pragma unroll
    for (int i = 0; i < G; ++i) { yA[i] = 0.0f; yB[i] = 0.0f; }
    int cur = 0;
    while (t + G <= t_end) {
        if (cur == 0) BODY_OUT(yA)
        else          BODY_OUT(yB)
        cur ^= 1;
        ++g; t += G;
    }

    // ---- tail (< G steps): slot g staged & forced complete by the last
    // output wait; plain compiler loads/stores (one conservative drain ok) ----
    {
        const int R = t_end - t;
        const float* slotf = (const float*)(lds + (g % NSLOT) * SLOTB);
        const unsigned d4 = d >> 2;
        for (int i = 0; i < R; ++i) {
            const float xx = slotf[d4 + i * FCC + fc];
            const float r  = __builtin_amdgcn_rcpf(1.0f - btg);
            btg *= BETAF;
            v1 = fmaf(BETAF, v1, OMBF * xx);
            const float v2 = v1 * r;
            const float dd = xx - v2;
            const float dp = xx - v2p;
            S = fmaf(OMBF * r, dd * dp - S, S);
            S = fmaxf(S, 0.0f);
            const float y = dd * __builtin_amdgcn_rsqf(S + EPSF);
            v2p = v2;
            if (t + i >= t_out && fc < FCC)
                Ofp[(size_t)(t + i) * FCC + fc] = y;
        }
    }

    // drain all asm VMEM before endpgm
    asm volatile("s_waitcnt vmcnt(0)" ::: "memory");
}

extern "C" void kernel_launch(void* const* d_in, const int* in_sizes, int n_in,
                              void* d_out, int out_size, void* d_ws, size_t ws_size,
                              hipStream_t stream) {
    const float* s = (const float*)d_in[0];
    float* out = (float*)d_out;
    dim3 grid(NN, NCHUNK);            // 16 x 7 = 112 blocks of 576 threads
    ewma_kernel<<<grid, dim3(576), 0, stream>>>(s, out);
}

// Round 11
// 153.890 us; speedup vs baseline: 1.1322x; 1.1322x over previous
//
#include <hip/hip_runtime.h>

// Problem: unbiased EWMA mean/var normalization over T, s:(16,2000,257,2) fp32.
// Layout: idx = ((n*T + t)*F + f)*C + c -> one n's data is CONTIGUOUS across
// (t, f, c); row per t = 514 floats = 2056 B.
//
// Strategy (v11 — v10's contiguous streaming blocks at FULL CU coverage):
//  - v10 post-mortem: linear staging + L3 residency cut HBM traffic 27%
//    (FETCH 110->68 MB) and DOUBLED per-CU delivery (13 -> ~21 GB/s/CU),
//    but the 16x7=112-block grid left 56% of CUs idle (110KB LDS -> 1
//    block/CU) -> aggregate fell. The lever is COVERAGE, not pattern.
//  - v11: NCHUNK=16, CLEN=125 -> grid 16x16 = 256 blocks = exactly 1/CU.
//    Warm redundancy raises logical reads 159->292 MB, but per-coverage time
//    improves monotonically: logical(c)/(16c) shrinks through c=16. Warm
//    re-reads are L3-resident (198 MB working set < 256 MB L3).
//  - Block = (n, chunk), 576 threads (9 waves). Staging = linear memcpy of
//    16-t rows via global_load_lds 16B/lane, 36 uniform 1KB-tile ops/group
//    (4 per wave -> one vmcnt literal). Compute: thread k owns series fc=k
//    (active fc<514; consecutive lanes -> consecutive LDS banks, conflict-
//    free; junk lanes never stored). Stores coalesced (contiguous 2KB/t).
//  - Ring of NSLOT=3 LDS slots, stage-2-ahead, sources clamped to the array
//    end (junk staged, never consumed). Sound waits (vmcnt retires in issue
//    order; queue peak 40 << 63):
//      warm:   vmcnt(4)  = keep stg(g+2), force stg(g+1).
//      output: vmcnt(20) = keep {stg(g+2)4, stores(g)16}, force stg(g+1)
//              and stores(g-1). Exact at fill AND steady state.
//      boundary (warm%16!=0; chunks 1-4 here): vmcnt(0) full drain.
//    Per-wave wait covers its OWN DMA ops; s_barrier then publishes all
//    waves' stage(g+1) writes to the block.
//  - y ping-pong + post-wait keepalives: stores(g) stay in flight through
//    group g+1; their data regs must not be recycled until retired.
//  - No asm-written VGPR lives across a backedge (v7/v8 crash class).
//  - WARM=512 (beta^512 ~ 5.9e-3, absmax unchanged 0.03125 across all runs).

#define NN 16
#define TT 2000
#define FCC 514
#define BPT 2056                  // bytes per t-row (514*4)
#define BETAF 0.99f
#define OMBF 0.01f
#define EPSF 1e-5f
#define NCHUNK 16
#define CLEN 125                  // 16 * 125 = 2000 exact
#define WARM 512
#define G 16                      // t-steps per group
#define GRPB (G * BPT)            // 32896 real bytes per group
#define SLOTB 36864               // 36 * 1024 staged bytes (uniform op pad)
#define NSLOT 3

// beta^i, i=0..16 (folds to literals)
__device__ __constant__ const float BP[G + 1] = {
    1.0f, 0.99f, 0.9801f, 0.970299f, 0.96059601f, 0.9509900499f,
    0.941480149401f, 0.93206534790699f, 0.9227446944279201f,
    0.9134272474836409f, 0.9042929750088045f, 0.8952500452587165f,
    0.8862975448061293f, 0.877434569357868f, 0.8686602236642894f,
    0.8599736214276465f, 0.8513738852133700f
};

// read 16 x's for this thread's series from slot (g%3); asm = opaque to the
// compiler's waitcnt model; lgkmcnt(0)+sched_barrier pins consumers below.
#define READX                                                                \
    float x[G];                                                              \
    {                                                                        \
        unsigned a = ldsbase + (unsigned)((g % NSLOT) * SLOTB) + d           \
                   + (unsigned)fc * 4u;                                      \
        _Pragma("unroll")                                                    \
        for (int i = 0; i < G; ++i) {                                        \
            asm volatile("ds_read_b32 %0, %1" : "=v"(x[i]) : "v"(a));        \
            a += BPT;                                                        \
        }                                                                    \
        asm volatile("s_waitcnt lgkmcnt(0)" ::: "memory");                   \
        __builtin_amdgcn_sched_barrier(0);                                   \
    }

// per-group lane-invariant scalars (16 pipelined v_rcp, off the chain)
#define RCPB                                                                 \
    float rr[G];                                                             \
    _Pragma("unroll")                                                        \
    for (int i = 0; i < G; ++i)                                              \
        rr[i] = __builtin_amdgcn_rcpf(1.0f - btg * BP[i]);                   \
    btg *= BP[G];

#define KEEP16(Y)                                                            \
    asm volatile("" :: "v"(Y[0]), "v"(Y[1]), "v"(Y[2]), "v"(Y[3]),           \
                       "v"(Y[4]), "v"(Y[5]), "v"(Y[6]), "v"(Y[7]),           \
                       "v"(Y[8]), "v"(Y[9]), "v"(Y[10]), "v"(Y[11]),         \
                       "v"(Y[12]), "v"(Y[13]), "v"(Y[14]), "v"(Y[15]));

// one output-phase group: compute into Y, store, counted wait, barrier
#define BODY_OUT(Y)                                                          \
    {                                                                        \
        READX                                                                \
        STAGE(g + 2);                                                        \
        RCPB                                                                 \
        float* pg = Ofp + (size_t)t * FCC + fc;                              \
        _Pragma("unroll")                                                    \
        for (int i = 0; i < G; ++i) {                                        \
            const float xx = x[i];                                           \
            const float r  = rr[i];                                          \
            v1 = fmaf(BETAF, v1, OMBF * xx);                                 \
            const float v2 = v1 * r;                                         \
            const float dd = xx - v2;                                        \
            const float dp = xx - v2p;                                       \
            S = fmaf(OMBF * r, dd * dp - S, S);                              \
            S = fmaxf(S, 0.0f);                                              \
            Y[i] = dd * __builtin_amdgcn_rsqf(S + EPSF);                     \
            v2p = v2;                                                        \
            if (fc < FCC)                                                    \
                asm volatile("global_store_dword %0, %1, off"                \
                             :: "v"(pg + i * FCC), "v"(Y[i]));               \
        }                                                                    \
        /* keep {stg(g+2)4, stores(g)16}; force stg(g+1) + stores(g-1) */    \
        asm volatile("s_waitcnt vmcnt(20)" ::: "memory");                    \
        __builtin_amdgcn_sched_barrier(0);                                   \
        KEEP16(yA) KEEP16(yB)                                                \
        __builtin_amdgcn_s_barrier();                                        \
    }

__global__ __launch_bounds__(576, 1)
void ewma_kernel(const float* __restrict__ s, float* __restrict__ out) {
    __shared__ char lds[NSLOT * SLOTB];   // 110592 B -> 1 block/CU

    const int lane = threadIdx.x & 63;
    const int wid  = threadIdx.x >> 6;
    const int fc   = threadIdx.x;         // series within n; active if < 514
    const int n    = blockIdx.x;
    const int chunk = blockIdx.y;

    const int t_out = chunk * CLEN;
    int t_end = t_out + CLEN; if (t_end > TT) t_end = TT;
    int t0 = t_out - WARM;     if (t0 < 0) t0 = 0;

    const char* Bn     = (const char*)s + (size_t)n * TT * BPT;
    const char* send16 = (const char*)s + (size_t)NN * TT * BPT - 16;
    const unsigned d   = (unsigned)((t0 & 1) * 8);   // (t0*2056) & 15

    const unsigned ldsbase =
        (unsigned)(uintptr_t)(__attribute__((address_space(3))) char*)lds;

    // 16B-aligned global base of group 0's span (GRPB is a multiple of 16)
    const char* Astage0 = Bn + (size_t)t0 * BPT - d;

    // stage group k -> slot k%3: 36 uniform 1KB-tile ops (4 per wave), 16B/lane,
    // sources clamped to array end (junk tiles staged, never consumed).
    auto STAGE = [&](int k) {
        const char* A = Astage0 + (size_t)k * GRPB;
        char* slot = lds + (k % NSLOT) * SLOTB;
        #pragma unroll
        for (int j = 0; j < 4; ++j) {
            const int o = wid * 4 + j;               // 0..35, all waves equal
            const char* src = A + o * 1024 + lane * 16;
            if (src > send16) src = send16;
            __builtin_amdgcn_global_load_lds(
                (const __attribute__((address_space(1))) void*)src,
                (__attribute__((address_space(3))) void*)(slot + o * 1024),
                16, 0, 0);
        }
    };

    // btg = beta^(t0+1) via double binary exponentiation (once per thread)
    float btg;
    {
        double bd = 0.99, acc = 0.99;
        int e = t0;
        while (e) { if (e & 1) acc *= bd; bd *= bd; e >>= 1; }
        btg = (float)acc;
    }

    float v1 = 0.0f, v2p = 0.0f, S = 0.0f;
    float* Ofp = out + (size_t)n * TT * FCC;

    // ---- prologue: stage groups 0,1; force stg(0), keep stg(1) ----
    STAGE(0); STAGE(1);
    asm volatile("s_waitcnt vmcnt(4)" ::: "memory");
    __builtin_amdgcn_sched_barrier(0);
    __builtin_amdgcn_s_barrier();

    int t = t0, g = 0;

    // ---- warm phase (no stores; y dead-codes away) ----
    while (t + G <= t_out) {
        READX
        STAGE(g + 2);
        RCPB
        #pragma unroll
        for (int i = 0; i < G; ++i) {
            const float xx = x[i];
            const float r  = rr[i];
            v1 = fmaf(BETAF, v1, OMBF * xx);
            const float v2 = v1 * r;
            const float dd = xx - v2;
            const float dp = xx - v2p;
            S = fmaf(OMBF * r, dd * dp - S, S);
            S = fmaxf(S, 0.0f);
            v2p = v2;
        }
        asm volatile("s_waitcnt vmcnt(4)" ::: "memory");  // keep stg(g+2)
        __builtin_amdgcn_sched_barrier(0);
        __builtin_amdgcn_s_barrier();
        ++g; t += G;
    }

    // ---- boundary group (straddles t_out; warm%16 != 0); full drain ----
    if (t < t_out && t + G <= t_end) {
        READX
        STAGE(g + 2);
        RCPB
        float* pg = Ofp + (size_t)t * FCC + fc;
        #pragma unroll
        for (int i = 0; i < G; ++i) {
            const float xx = x[i];
            const float r  = rr[i];
            v1 = fmaf(BETAF, v1, OMBF * xx);
            const float v2 = v1 * r;
            const float dd = xx - v2;
            const float dp = xx - v2p;
            S = fmaf(OMBF * r, dd * dp - S, S);
            S = fmaxf(S, 0.0f);
            const float y = dd * __builtin_amdgcn_rsqf(S + EPSF);
            v2p = v2;
            if (t + i >= t_out && fc < FCC)
                asm volatile("global_store_dword %0, %1, off"
                             :: "v"(pg + i * FCC), "v"(y));
        }
        asm volatile("s_waitcnt vmcnt(0)" ::: "memory");
        __builtin_amdgcn_sched_barrier(0);
        __builtin_amdgcn_s_barrier();
        ++g; t += G;
    }

    // ---- output phase: y ping-pong, uniform vmcnt(20) ----
    float yA[G], yB[G];
    #pragma unroll
    for (int i = 0; i < G; ++i) { yA[i] = 0.0f; yB[i] = 0.0f; }
    int cur = 0;
    while (t + G <= t_end) {
        if (cur == 0) BODY_OUT(yA)
        else          BODY_OUT(yB)
        cur ^= 1;
        ++g; t += G;
    }

    // ---- tail (< G steps): slot g was staged by the ring and forced
    // complete by the last group's wait; plain compiler loads/stores ----
    {
        const int R = t_end - t;
        const float* slotf = (const float*)(lds + (g % NSLOT) * SLOTB);
        const unsigned d4 = d >> 2;
        for (int i = 0; i < R; ++i) {
            const float xx = slotf[d4 + i * FCC + fc];
            const float r  = __builtin_amdgcn_rcpf(1.0f - btg);
            btg *= BETAF;
            v1 = fmaf(BETAF, v1, OMBF * xx);
            const float v2 = v1 * r;
            const float dd = xx - v2;
            const float dp = xx - v2p;
            S = fmaf(OMBF * r, dd * dp - S, S);
            S = fmaxf(S, 0.0f);
            const float y = dd * __builtin_amdgcn_rsqf(S + EPSF);
            v2p = v2;
            if (t + i >= t_out && fc < FCC)
                Ofp[(size_t)(t + i) * FCC + fc] = y;
        }
    }

    // drain all asm VMEM before endpgm
    asm volatile("s_waitcnt vmcnt(0)" ::: "memory");
}

extern "C" void kernel_launch(void* const* d_in, const int* in_sizes, int n_in,
                              void* d_out, int out_size, void* d_ws, size_t ws_size,
                              hipStream_t stream) {
    const float* s = (const float*)d_in[0];
    float* out = (float*)d_out;
    dim3 grid(NN, NCHUNK);            // 16 x 16 = 256 blocks of 576 threads
    ewma_kernel<<<grid, dim3(576), 0, stream>>>(s, out);
}